// Round 17
// baseline (562.572 us; speedup 1.0000x reference)
//
#include <hip/hip_runtime.h>
#include <hip/hip_bf16.h>
#include <cstdint>
#include <cstddef>

typedef unsigned short u16;
typedef __attribute__((ext_vector_type(8))) __bf16 bf16x8;
typedef __attribute__((ext_vector_type(4))) float f32x4;

#define DEV __device__ __forceinline__

// ---------- helpers ----------
DEV u16 f2bf(float f) {
    union { float f; uint32_t u; } c{f};
    uint32_t u = c.u;
    uint32_t r = (u + 0x7fffu + ((u >> 16) & 1u)) >> 16;
    return (u16)r;
}
DEV float bf2f(u16 u) {
    union { uint32_t u; float f; } c{(uint32_t)u << 16};
    return c.f;
}
DEV void gload16(const void* g, void* l) {
    __builtin_amdgcn_global_load_lds((const __attribute__((address_space(1))) void*)g,
                                     (__attribute__((address_space(3))) void*)l, 16, 0, 0);
}
DEV void ntstore(float* p, float v) { __builtin_nontemporal_store(v, p); }
DEV void ntstore4(float* p, float4 v) {
    f32x4 w = {v.x, v.y, v.z, v.w};
    __builtin_nontemporal_store(w, (f32x4*)p);
}

// Problem constants
#define Bb 4
#define Ss 2048
#define KVv 2048
#define Dd 2048
#define Tcat 4096  // KV + S

// ---------- fused pre-QKV streaming: conversions + pastK + pastV ----------
// [0,16384): x conv | [16384,28672): W conv | [28672,45056): pastK | [45056,61440): pastV
__global__ __launch_bounds__(256) void k_pre(const float* __restrict__ x,
                                             const float* __restrict__ w0,
                                             const float* __restrict__ w1,
                                             const float* __restrict__ w2,
                                             const float* __restrict__ pk,
                                             const float* __restrict__ pv,
                                             u16* __restrict__ x_bf,
                                             u16* __restrict__ w_bf,
                                             float* __restrict__ ck,
                                             float* __restrict__ cv,
                                             u16* __restrict__ kcat,
                                             u16* __restrict__ vt) {
    __shared__ float tile[32][33];
    const int idx = blockIdx.x;
    const int tid = threadIdx.x;

    if (idx < 28672) {
        // conversions
        const float* src;
        u16* dst;
        int i;
        if (idx < 16384) {
            src = x; dst = x_bf; i = idx * 256 + tid;
        } else {
            int wid = idx - 16384;
            int which = wid >> 12;
            src = (which == 0) ? w0 : (which == 1) ? w1 : w2;
            dst = w_bf + (size_t)which * Dd * Dd;
            i = (wid & 4095) * 256 + tid;
        }
        float4 v = ((const float4*)src)[i];
        ushort4 o;
        o.x = f2bf(v.x); o.y = f2bf(v.y); o.z = f2bf(v.z); o.w = f2bf(v.w);
        ((ushort4*)dst)[i] = o;
    } else if (idx < 45056) {
        // pastK: f32 copy -> cache_k (nt) + bf16 -> kcat
        size_t i = (size_t)(idx - 28672) * 256 + tid;
        float4 v = ((const float4*)pk)[i];
        size_t e = i * 4;
        int b = (int)(e >> 22);
        size_t off = e + ((size_t)b << 22);
        ntstore4(ck + off, v);
        ushort4 o;
        o.x = f2bf(v.x); o.y = f2bf(v.y); o.z = f2bf(v.z); o.w = f2bf(v.w);
        *(ushort4*)(kcat + off) = o;
    } else {
        // pastV: f32 copy -> cache_v (nt) + bf16 transposed -> vt
        int vid = idx - 45056;
        int b = vid >> 12;
        int rem = vid & 4095;
        int t0 = (rem & 63) * 32;
        int d0 = (rem >> 6) * 32;
        int tx = tid & 31, ty = tid >> 5;
#pragma unroll
        for (int i = 0; i < 4; ++i) {
            int t = ty + i * 8;
            float val = pv[((size_t)b * KVv + t0 + t) * Dd + d0 + tx];
            ntstore(&cv[((size_t)b * Tcat + t0 + t) * Dd + d0 + tx], val);
            tile[t][tx] = val;
        }
        __syncthreads();
#pragma unroll
        for (int i = 0; i < 4; ++i) {
            int d = ty + i * 8;
            vt[((size_t)b * Dd + d0 + d) * Tcat + t0 + tx] = f2bf(tile[tx][d]);
        }
    }
}

// new V rows: cache_v[b][KVv+t][d] f32 (L3-hot from QKV epilogue) -> vt bf16 transposed
__global__ __launch_bounds__(256) void k_vup(const float* __restrict__ cv,
                                             u16* __restrict__ vt) {
    __shared__ float tile[32][33];
    int b = blockIdx.z;
    int t0 = blockIdx.x * 32 + KVv;
    int d0 = blockIdx.y * 32;
    int tx = threadIdx.x & 31, ty = threadIdx.x >> 5;
#pragma unroll
    for (int i = 0; i < 4; ++i) {
        int t = ty + i * 8;
        tile[t][tx] = cv[((size_t)b * Tcat + t0 + t) * Dd + d0 + tx];
    }
    __syncthreads();
#pragma unroll
    for (int i = 0; i < 4; ++i) {
        int d = ty + i * 8;
        vt[((size_t)b * Dd + d0 + d) * Tcat + t0 + tx] = f2bf(tile[tx][d]);
    }
}

// ---------- 256x256x64 8-phase GEMM: C[m,n] = sum_k A[m,k]*B[n,k] ----------
enum { MQKV = 0, MS = 1, MPV = 2 };

#define STAGE(bufi, isA, h, t)                                                        \
    do {                                                                              \
        const u16* gsrc = ((isA) ? A : Bm) +                                          \
                          (size_t)(((isA) ? m0 : n0) + (h) * 128) * (size_t)Kdim +    \
                          (size_t)(t) * 64;                                           \
        u16* ld = &lds[(bufi) * 32768 + ((isA) ? 0 : 16384) + (h) * 8192];            \
        gload16(gsrc + soff0, ld + tid * 8);                                          \
        gload16(gsrc + soff1, ld + 4096 + tid * 8);                                   \
    } while (0)

#define ENDS_BAR __builtin_amdgcn_s_barrier()

#define ENDS_VM(cond)                                                  \
    do {                                                               \
        if (cond) asm volatile("s_waitcnt vmcnt(4)" ::: "memory");     \
        else      asm volatile("s_waitcnt vmcnt(0)" ::: "memory");     \
        __builtin_amdgcn_s_barrier();                                  \
    } while (0)

// register-reuse fragment loads (operands read ONCE per tile)
#define RD_A(bufi, MH)                                                              \
    do {                                                                            \
        const u16* abase_ = &lds[(bufi) * 32768];                                   \
        _Pragma("unroll") for (int mfq = 0; mfq < 4; ++mfq) {                       \
            int gmf = ((MH) * 4 + mfq) * 2 + wr;                                    \
            avH[mfq][0] = *(const bf16x8*)&abase_[gmf * 1024 + rdo0];               \
            avH[mfq][1] = *(const bf16x8*)&abase_[gmf * 1024 + rdo1];               \
        }                                                                           \
    } while (0)

#define RD_B(bufi, NH, bvar)                                                        \
    do {                                                                            \
        const u16* bbase_ = &lds[(bufi) * 32768 + 16384];                           \
        _Pragma("unroll") for (int nfq = 0; nfq < 2; ++nfq) {                       \
            int gnf = ((NH) * 2 + nfq) * 4 + wc;                                    \
            bvar[nfq][0] = *(const bf16x8*)&bbase_[gnf * 1024 + rdo0];              \
            bvar[nfq][1] = *(const bf16x8*)&bbase_[gnf * 1024 + rdo1];              \
        }                                                                           \
    } while (0)

#define PHASE(MH, NH, bvar, READS, STAGE_STMT, ENDSYNC)                                \
    do {                                                                               \
        READS;                                                                         \
        STAGE_STMT;                                                                    \
        __builtin_amdgcn_s_barrier();                                                  \
        asm volatile("s_waitcnt lgkmcnt(0)" ::: "memory");                             \
        __builtin_amdgcn_s_setprio(1);                                                 \
        _Pragma("unroll") for (int nfq = 0; nfq < 2; ++nfq)                            \
        _Pragma("unroll") for (int mfq = 0; mfq < 4; ++mfq) {                          \
            acc[(MH) * 4 + mfq][(NH) * 2 + nfq] = __builtin_amdgcn_mfma_f32_16x16x32_bf16( \
                avH[mfq][0], bvar[nfq][0], acc[(MH) * 4 + mfq][(NH) * 2 + nfq], 0, 0, 0); \
            acc[(MH) * 4 + mfq][(NH) * 2 + nfq] = __builtin_amdgcn_mfma_f32_16x16x32_bf16( \
                avH[mfq][1], bvar[nfq][1], acc[(MH) * 4 + mfq][(NH) * 2 + nfq], 0, 0, 0); \
        }                                                                              \
        __builtin_amdgcn_s_setprio(0);                                                 \
        ENDSYNC;                                                                       \
    } while (0)

// 2D XCD chunking: each XCD owns one cw x ch rectangle of the (bx,by) grid.
template <int MODE>
__global__ __launch_bounds__(512, 2) void gemm8(const u16* __restrict__ A,
                                                const u16* __restrict__ Bm, int Kdim,
                                                size_t sAz, size_t sBz,
                                                int cw, int ch,
                                                u16* __restrict__ p0, u16* __restrict__ p1,
                                                float* __restrict__ f0,
                                                float* __restrict__ f1) {
    __shared__ u16 lds[65536]; // 128 KiB
    const int tid = threadIdx.x;
    const int lane = tid & 63;
    const int w = tid >> 6;
    const int wr = w >> 2; // 0..1 (M)
    const int wc = w & 3;  // 0..3 (N)

    const int gx = gridDim.x, gy = gridDim.y;
    int orig = blockIdx.x + gx * (blockIdx.y + gy * blockIdx.z);
    int c = orig & 7;          // XCD chunk
    int within = orig >> 3;    // time order within chunk
    int ncx = gx / cw;
    int rpz = ncx * (gy / ch);
    int z = c / rpz;
    int r = c % rpz;
    int rx = r % ncx, ry = r / ncx;
    int bx = rx * cw + within % cw;
    int by = ry * ch + within / cw;
    int bz = z;

    A += (size_t)bz * sAz;
    Bm += (size_t)bz * sBz;
    const int m0 = by * 256;
    const int n0 = bx * 256;

    const int c3 = tid & 7;
    const int r0_ = tid >> 3;
    const int r1_ = r0_ + 64;
    const size_t soff0 = (size_t)r0_ * (size_t)Kdim + (size_t)((c3 ^ (r0_ & 7)) * 8);
    const size_t soff1 = (size_t)r1_ * (size_t)Kdim + (size_t)((c3 ^ (r1_ & 7)) * 8);

    const int l15 = lane & 15;
    const int q = lane >> 4;
    const int s3 = l15 & 7;
    const int rdo0 = l15 * 64 + ((q ^ s3) * 8);
    const int rdo1 = l15 * 64 + (((4 + q) ^ s3) * 8);

    f32x4 acc[8][4] = {};
    bf16x8 avH[4][2];
    bf16x8 bv0[2][2];
    bf16x8 bv1[2][2];

    const int nt = Kdim >> 6;

    STAGE(0, 1, 0, 0); STAGE(0, 1, 1, 0); STAGE(0, 0, 0, 0); STAGE(0, 0, 1, 0);
    STAGE(1, 1, 0, 1); STAGE(1, 0, 0, 1);
    asm volatile("s_waitcnt vmcnt(4)" ::: "memory");
    __builtin_amdgcn_s_barrier();

    for (int t = 0; t < nt; t += 2) {
        const bool more = (t + 2) < nt;
        const bool more3 = (t + 3) < nt;
        // tile t from buf0: quadrant Gray order (0,0)->(0,1)->(1,1)->(1,0)
        PHASE(0, 0, bv0, RD_A(0, 0); RD_B(0, 0, bv0), STAGE(1, 1, 1, t + 1), ENDS_BAR);
        PHASE(0, 1, bv1, RD_B(0, 1, bv1),             STAGE(1, 0, 1, t + 1), ENDS_BAR);
        PHASE(1, 1, bv1, RD_A(0, 1),                  if (more) STAGE(0, 1, 0, t + 2), ENDS_BAR);
        PHASE(1, 0, bv0, ;,                           if (more) STAGE(0, 0, 0, t + 2), ENDS_VM(more));
        // tile t+1 from buf1
        PHASE(0, 0, bv0, RD_A(1, 0); RD_B(1, 0, bv0), if (more) STAGE(0, 1, 1, t + 2), ENDS_BAR);
        PHASE(0, 1, bv1, RD_B(1, 1, bv1),             if (more) STAGE(0, 0, 1, t + 2), ENDS_BAR);
        PHASE(1, 1, bv1, RD_A(1, 1),                  if (more3) STAGE(1, 1, 0, t + 3), ENDS_BAR);
        PHASE(1, 0, bv0, ;,                           if (more3) STAGE(1, 0, 0, t + 3), ENDS_VM(more3));
    }

    // epilogue: C/D frag layout col=lane&15, row=(lane>>4)*4+r
    const int orow = (lane >> 4) * 4;
    const int ocol = lane & 15;
#pragma unroll
    for (int mf = 0; mf < 8; ++mf) {
#pragma unroll
        for (int nf = 0; nf < 4; ++nf) {
#pragma unroll
            for (int r2 = 0; r2 < 4; ++r2) {
                int gm = m0 + (mf * 2 + wr) * 16 + orow + r2;
                int gn = n0 + (nf * 4 + wc) * 16 + ocol;
                float v = acc[mf][nf][r2];
                if constexpr (MODE == MQKV) {
                    if (gn < 2048) {
                        p0[(size_t)gm * Dd + gn] = f2bf(v); // Q bf16
                    } else {
                        size_t crow = (size_t)gm + (size_t)(((unsigned)gm >> 11) + 1) * Ss;
                        if (gn < 4096) {
                            p1[crow * Dd + (gn - 2048)] = f2bf(v);       // kcat bf16
                            ntstore(&f0[crow * Dd + (gn - 2048)], v);    // cache_k f32
                        } else {
                            f1[crow * Dd + (gn - 4096)] = v;             // cache_v f32 (read by vup)
                        }
                    }
                } else if constexpr (MODE == MS) {
                    p0[(size_t)bz * Ss * Tcat + (size_t)gm * Tcat + gn] = f2bf(v);
                } else { // MPV
                    ntstore(&f0[(size_t)bz * Ss * Dd + (size_t)gm * Dd + gn],
                            rintf(v * 1e4f) * 1e-4f); // out: final -> stream
                }
            }
        }
    }
}

// ---------- softmax ----------
__global__ __launch_bounds__(256) void k_softmax(u16* __restrict__ SP) {
    const size_t row = blockIdx.x;
    u16* p = SP + row * Tcat;
    const int tid = threadIdx.x;
    const int lane = tid & 63;
    const int wv = tid >> 6;
    const float RS = 0.022097086912079608f; // 1/sqrt(2048)

    ushort4 raw[4];
    const ushort4* src = (const ushort4*)(p + tid * 16);
#pragma unroll
    for (int i = 0; i < 4; ++i) raw[i] = src[i];

    float v[16];
#pragma unroll
    for (int i = 0; i < 4; ++i) {
        v[i * 4 + 0] = bf2f(raw[i].x) * RS;
        v[i * 4 + 1] = bf2f(raw[i].y) * RS;
        v[i * 4 + 2] = bf2f(raw[i].z) * RS;
        v[i * 4 + 3] = bf2f(raw[i].w) * RS;
    }
    float mx = v[0];
#pragma unroll
    for (int i = 1; i < 16; ++i) mx = fmaxf(mx, v[i]);
#pragma unroll
    for (int s = 32; s; s >>= 1) mx = fmaxf(mx, __shfl_xor(mx, s));
    __shared__ float redm[4];
    if (lane == 0) redm[wv] = mx;
    __syncthreads();
    mx = fmaxf(fmaxf(redm[0], redm[1]), fmaxf(redm[2], redm[3]));

    float sum = 0.f;
#pragma unroll
    for (int i = 0; i < 16; ++i) {
        v[i] = __expf(v[i] - mx);
        sum += v[i];
    }
#pragma unroll
    for (int s = 32; s; s >>= 1) sum += __shfl_xor(sum, s);
    __shared__ float reds[4];
    if (lane == 0) reds[wv] = sum;
    __syncthreads();
    sum = reds[0] + reds[1] + reds[2] + reds[3];
    float inv = 1.0f / sum;

    ushort4* dst = (ushort4*)(p + tid * 16);
#pragma unroll
    for (int i = 0; i < 4; ++i) {
        ushort4 o;
        o.x = f2bf(v[i * 4 + 0] * inv);
        o.y = f2bf(v[i * 4 + 1] * inv);
        o.z = f2bf(v[i * 4 + 2] * inv);
        o.w = f2bf(v[i * 4 + 3] * inv);
        dst[i] = o;
    }
}

// ---------- launch ----------
extern "C" void kernel_launch(void* const* d_in, const int* in_sizes, int n_in,
                              void* d_out, int out_size, void* d_ws, size_t ws_size,
                              hipStream_t stream) {
    const float* x      = (const float*)d_in[0];
    const float* past_k = (const float*)d_in[1];
    const float* past_v = (const float*)d_in[2];
    const float* Wq     = (const float*)d_in[3];
    const float* Wk     = (const float*)d_in[4];
    const float* Wv     = (const float*)d_in[5];

    float* out     = (float*)d_out;
    float* cache_k = out + (size_t)Bb * Ss * Dd;
    float* cache_v = cache_k + (size_t)Bb * Tcat * Dd;

    u16* x_bf    = (u16*)d_ws;
    u16* wqkv_bf = x_bf + (size_t)Bb * Ss * Dd;
    u16* q_bf    = wqkv_bf + (size_t)3 * Dd * Dd;
    u16* kcat    = q_bf + (size_t)Bb * Ss * Dd;
    u16* vt      = kcat + (size_t)Bb * Tcat * Dd;
    u16* sp      = vt + (size_t)Bb * Dd * Tcat;

    // fused pre-QKV streaming: conversions + pastK + pastV (all independent of QKV)
    k_pre<<<61440, 256, 0, stream>>>(x, Wq, Wk, Wv, past_k, past_v,
                                     x_bf, wqkv_bf, cache_k, cache_v, kcat, vt);

    // fused QKV projection: M=8192, N=6144, K=2048 — 256^2 tile
    gemm8<MQKV><<<dim3(24, 32, 1), 512, 0, stream>>>(x_bf, wqkv_bf, Dd, 0, 0, 6, 16,
                                                     q_bf, kcat, cache_k, cache_v);

    // transpose new V rows from L3-hot cache_v into vt (only QKV-dependent streamer)
    k_vup<<<dim3(Ss / 32, Dd / 32, Bb), 256, 0, stream>>>(cache_v, vt);

    // scores: per b: M=2048, N=4096, K=2048 -> sp
    gemm8<MS><<<dim3(16, 8, Bb), 512, 0, stream>>>(q_bf, kcat, Dd,
                                                   (size_t)Ss * Dd, (size_t)Tcat * Dd, 8, 8,
                                                   sp, nullptr, nullptr, nullptr);
    // softmax rows
    k_softmax<<<Bb * Ss, 256, 0, stream>>>(sp);

    // PV: per b: M=2048, N=2048, K=4096 -> out (rounded)
    gemm8<MPV><<<dim3(8, 8, Bb), 512, 0, stream>>>(sp, vt, Tcat,
                                                   (size_t)Ss * Tcat, (size_t)Dd * Tcat, 8, 4,
                                                   nullptr, nullptr, out, nullptr);
}

// Round 18
// 559.071 us; speedup vs baseline: 1.0063x; 1.0063x over previous
//
#include <hip/hip_runtime.h>
#include <hip/hip_bf16.h>
#include <cstdint>
#include <cstddef>

typedef unsigned short u16;
typedef __attribute__((ext_vector_type(8))) __bf16 bf16x8;
typedef __attribute__((ext_vector_type(4))) float f32x4;

#define DEV __device__ __forceinline__

// ---------- helpers ----------
DEV u16 f2bf(float f) {
    union { float f; uint32_t u; } c{f};
    uint32_t u = c.u;
    uint32_t r = (u + 0x7fffu + ((u >> 16) & 1u)) >> 16;
    return (u16)r;
}
DEV float bf2f(u16 u) {
    union { uint32_t u; float f; } c{(uint32_t)u << 16};
    return c.f;
}
DEV void gload16(const void* g, void* l) {
    __builtin_amdgcn_global_load_lds((const __attribute__((address_space(1))) void*)g,
                                     (__attribute__((address_space(3))) void*)l, 16, 0, 0);
}
DEV void ntstore(float* p, float v) { __builtin_nontemporal_store(v, p); }
DEV void ntstore4(float* p, float4 v) {
    f32x4 w = {v.x, v.y, v.z, v.w};
    __builtin_nontemporal_store(w, (f32x4*)p);
}

// Problem constants
#define Bb 4
#define Ss 2048
#define KVv 2048
#define Dd 2048
#define Tcat 4096  // KV + S

// ---------- fused conversion: x (16384 blocks) + Wq/Wk/Wv (3x4096 blocks) ----------
__global__ __launch_bounds__(256) void k_conv(const float* __restrict__ x,
                                              const float* __restrict__ w0,
                                              const float* __restrict__ w1,
                                              const float* __restrict__ w2,
                                              u16* __restrict__ x_bf,
                                              u16* __restrict__ w_bf) {
    int idx = blockIdx.x;
    const float* src;
    u16* dst;
    int i;
    if (idx < 16384) {
        src = x; dst = x_bf; i = idx * 256 + threadIdx.x;
    } else {
        int wid = idx - 16384;
        int which = wid >> 12;           // /4096
        src = (which == 0) ? w0 : (which == 1) ? w1 : w2;
        dst = w_bf + (size_t)which * Dd * Dd;
        i = (wid & 4095) * 256 + threadIdx.x;
    }
    float4 v = ((const float4*)src)[i];
    ushort4 o;
    o.x = f2bf(v.x); o.y = f2bf(v.y); o.z = f2bf(v.z); o.w = f2bf(v.w);
    ((ushort4*)dst)[i] = o;
}

// ---------- fused post-QKV streaming: pastK copy + pastV transpose + newV transpose ----------
// [0,16384): pastK  | [16384,32768): pastV | [32768,49152): vup (new V rows from cache_v)
__global__ __launch_bounds__(256) void k_past(const float* __restrict__ pk,
                                              const float* __restrict__ pv,
                                              float* __restrict__ ck,
                                              float* __restrict__ cv,
                                              u16* __restrict__ kcat,
                                              u16* __restrict__ vt) {
    __shared__ float tile[32][33];
    const int idx = blockIdx.x;
    const int tid = threadIdx.x;

    if (idx < 16384) {
        // pastK: f32 copy -> cache_k (nt) + bf16 -> kcat
        size_t i = (size_t)idx * 256 + tid;
        float4 v = ((const float4*)pk)[i];
        size_t e = i * 4;
        int b = (int)(e >> 22);
        size_t off = e + ((size_t)b << 22);
        ntstore4(ck + off, v);
        ushort4 o;
        o.x = f2bf(v.x); o.y = f2bf(v.y); o.z = f2bf(v.z); o.w = f2bf(v.w);
        *(ushort4*)(kcat + off) = o;
    } else if (idx < 32768) {
        // pastV: f32 copy -> cache_v (nt) + bf16 transposed -> vt
        int vid = idx - 16384;
        int b = vid >> 12;
        int rem = vid & 4095;
        int t0 = (rem & 63) * 32;
        int d0 = (rem >> 6) * 32;
        int tx = tid & 31, ty = tid >> 5;
#pragma unroll
        for (int i = 0; i < 4; ++i) {
            int t = ty + i * 8;
            float val = pv[((size_t)b * KVv + t0 + t) * Dd + d0 + tx];
            ntstore(&cv[((size_t)b * Tcat + t0 + t) * Dd + d0 + tx], val);
            tile[t][tx] = val;
        }
        __syncthreads();
#pragma unroll
        for (int i = 0; i < 4; ++i) {
            int d = ty + i * 8;
            vt[((size_t)b * Dd + d0 + d) * Tcat + t0 + tx] = f2bf(tile[tx][d]);
        }
    } else {
        // vup: new V rows cache_v[b][KVv+t][d] f32 -> vt bf16 transposed
        int vid = idx - 32768;
        int b = vid >> 12;
        int rem = vid & 4095;
        int t0 = (rem & 63) * 32 + KVv;
        int d0 = (rem >> 6) * 32;
        int tx = tid & 31, ty = tid >> 5;
#pragma unroll
        for (int i = 0; i < 4; ++i) {
            int t = ty + i * 8;
            tile[t][tx] = cv[((size_t)b * Tcat + t0 + t) * Dd + d0 + tx];
        }
        __syncthreads();
#pragma unroll
        for (int i = 0; i < 4; ++i) {
            int d = ty + i * 8;
            vt[((size_t)b * Dd + d0 + d) * Tcat + t0 + tx] = f2bf(tile[tx][d]);
        }
    }
}

// ---------- 256x256x64 8-phase GEMM: C[m,n] = sum_k A[m,k]*B[n,k] ----------
enum { MQKV = 0, MS = 1, MPV = 2 };

#define STAGE(bufi, isA, h, t)                                                        \
    do {                                                                              \
        const u16* gsrc = ((isA) ? A : Bm) +                                          \
                          (size_t)(((isA) ? m0 : n0) + (h) * 128) * (size_t)Kdim +    \
                          (size_t)(t) * 64;                                           \
        u16* ld = &lds[(bufi) * 32768 + ((isA) ? 0 : 16384) + (h) * 8192];            \
        gload16(gsrc + soff0, ld + tid * 8);                                          \
        gload16(gsrc + soff1, ld + 4096 + tid * 8);                                   \
    } while (0)

#define ENDS_BAR __builtin_amdgcn_s_barrier()

#define ENDS_VM(cond)                                                  \
    do {                                                               \
        if (cond) asm volatile("s_waitcnt vmcnt(4)" ::: "memory");     \
        else      asm volatile("s_waitcnt vmcnt(0)" ::: "memory");     \
        __builtin_amdgcn_s_barrier();                                  \
    } while (0)

// register-reuse fragment loads (operands read ONCE per tile)
#define RD_A(bufi, MH)                                                              \
    do {                                                                            \
        const u16* abase_ = &lds[(bufi) * 32768];                                   \
        _Pragma("unroll") for (int mfq = 0; mfq < 4; ++mfq) {                       \
            int gmf = ((MH) * 4 + mfq) * 2 + wr;                                    \
            avH[mfq][0] = *(const bf16x8*)&abase_[gmf * 1024 + rdo0];               \
            avH[mfq][1] = *(const bf16x8*)&abase_[gmf * 1024 + rdo1];               \
        }                                                                           \
    } while (0)

#define RD_B(bufi, NH, bvar)                                                        \
    do {                                                                            \
        const u16* bbase_ = &lds[(bufi) * 32768 + 16384];                           \
        _Pragma("unroll") for (int nfq = 0; nfq < 2; ++nfq) {                       \
            int gnf = ((NH) * 2 + nfq) * 4 + wc;                                    \
            bvar[nfq][0] = *(const bf16x8*)&bbase_[gnf * 1024 + rdo0];              \
            bvar[nfq][1] = *(const bf16x8*)&bbase_[gnf * 1024 + rdo1];              \
        }                                                                           \
    } while (0)

#define PHASE(MH, NH, bvar, READS, STAGE_STMT, ENDSYNC)                                \
    do {                                                                               \
        READS;                                                                         \
        STAGE_STMT;                                                                    \
        __builtin_amdgcn_s_barrier();                                                  \
        asm volatile("s_waitcnt lgkmcnt(0)" ::: "memory");                             \
        __builtin_amdgcn_s_setprio(1);                                                 \
        _Pragma("unroll") for (int nfq = 0; nfq < 2; ++nfq)                            \
        _Pragma("unroll") for (int mfq = 0; mfq < 4; ++mfq) {                          \
            acc[(MH) * 4 + mfq][(NH) * 2 + nfq] = __builtin_amdgcn_mfma_f32_16x16x32_bf16( \
                avH[mfq][0], bvar[nfq][0], acc[(MH) * 4 + mfq][(NH) * 2 + nfq], 0, 0, 0); \
            acc[(MH) * 4 + mfq][(NH) * 2 + nfq] = __builtin_amdgcn_mfma_f32_16x16x32_bf16( \
                avH[mfq][1], bvar[nfq][1], acc[(MH) * 4 + mfq][(NH) * 2 + nfq], 0, 0, 0); \
        }                                                                              \
        __builtin_amdgcn_s_setprio(0);                                                 \
        ENDSYNC;                                                                       \
    } while (0)

// 2D XCD chunking: each XCD owns one cw x ch rectangle of the (bx,by) grid.
template <int MODE>
__global__ __launch_bounds__(512, 2) void gemm8(const u16* __restrict__ A,
                                                const u16* __restrict__ Bm, int Kdim,
                                                size_t sAz, size_t sBz,
                                                int cw, int ch,
                                                u16* __restrict__ p0, u16* __restrict__ p1,
                                                float* __restrict__ f0,
                                                float* __restrict__ f1) {
    __shared__ u16 lds[65536]; // 128 KiB
    const int tid = threadIdx.x;
    const int lane = tid & 63;
    const int w = tid >> 6;
    const int wr = w >> 2; // 0..1 (M)
    const int wc = w & 3;  // 0..3 (N)

    const int gx = gridDim.x, gy = gridDim.y;
    int orig = blockIdx.x + gx * (blockIdx.y + gy * blockIdx.z);
    int c = orig & 7;          // XCD chunk
    int within = orig >> 3;    // time order within chunk
    int ncx = gx / cw;
    int rpz = ncx * (gy / ch);
    int z = c / rpz;
    int r = c % rpz;
    int rx = r % ncx, ry = r / ncx;
    int bx = rx * cw + within % cw;
    int by = ry * ch + within / cw;
    int bz = z;

    A += (size_t)bz * sAz;
    Bm += (size_t)bz * sBz;
    const int m0 = by * 256;
    const int n0 = bx * 256;

    const int c3 = tid & 7;
    const int r0_ = tid >> 3;
    const int r1_ = r0_ + 64;
    const size_t soff0 = (size_t)r0_ * (size_t)Kdim + (size_t)((c3 ^ (r0_ & 7)) * 8);
    const size_t soff1 = (size_t)r1_ * (size_t)Kdim + (size_t)((c3 ^ (r1_ & 7)) * 8);

    const int l15 = lane & 15;
    const int q = lane >> 4;
    const int s3 = l15 & 7;
    const int rdo0 = l15 * 64 + ((q ^ s3) * 8);
    const int rdo1 = l15 * 64 + (((4 + q) ^ s3) * 8);

    f32x4 acc[8][4] = {};
    bf16x8 avH[4][2];
    bf16x8 bv0[2][2];
    bf16x8 bv1[2][2];

    const int nt = Kdim >> 6;

    STAGE(0, 1, 0, 0); STAGE(0, 1, 1, 0); STAGE(0, 0, 0, 0); STAGE(0, 0, 1, 0);
    STAGE(1, 1, 0, 1); STAGE(1, 0, 0, 1);
    asm volatile("s_waitcnt vmcnt(4)" ::: "memory");
    __builtin_amdgcn_s_barrier();

    for (int t = 0; t < nt; t += 2) {
        const bool more = (t + 2) < nt;
        const bool more3 = (t + 3) < nt;
        // tile t from buf0: quadrant Gray order (0,0)->(0,1)->(1,1)->(1,0)
        PHASE(0, 0, bv0, RD_A(0, 0); RD_B(0, 0, bv0), STAGE(1, 1, 1, t + 1), ENDS_BAR);
        PHASE(0, 1, bv1, RD_B(0, 1, bv1),             STAGE(1, 0, 1, t + 1), ENDS_BAR);
        PHASE(1, 1, bv1, RD_A(0, 1),                  if (more) STAGE(0, 1, 0, t + 2), ENDS_BAR);
        PHASE(1, 0, bv0, ;,                           if (more) STAGE(0, 0, 0, t + 2), ENDS_VM(more));
        // tile t+1 from buf1
        PHASE(0, 0, bv0, RD_A(1, 0); RD_B(1, 0, bv0), if (more) STAGE(0, 1, 1, t + 2), ENDS_BAR);
        PHASE(0, 1, bv1, RD_B(1, 1, bv1),             if (more) STAGE(0, 0, 1, t + 2), ENDS_BAR);
        PHASE(1, 1, bv1, RD_A(1, 1),                  if (more3) STAGE(1, 1, 0, t + 3), ENDS_BAR);
        PHASE(1, 0, bv0, ;,                           if (more3) STAGE(1, 0, 0, t + 3), ENDS_VM(more3));
    }

    // epilogue: C/D frag layout col=lane&15, row=(lane>>4)*4+r
    const int orow = (lane >> 4) * 4;
    const int ocol = lane & 15;
#pragma unroll
    for (int mf = 0; mf < 8; ++mf) {
#pragma unroll
        for (int nf = 0; nf < 4; ++nf) {
#pragma unroll
            for (int r2 = 0; r2 < 4; ++r2) {
                int gm = m0 + (mf * 2 + wr) * 16 + orow + r2;
                int gn = n0 + (nf * 4 + wc) * 16 + ocol;
                float v = acc[mf][nf][r2];
                if constexpr (MODE == MQKV) {
                    if (gn < 2048) {
                        p0[(size_t)gm * Dd + gn] = f2bf(v); // Q bf16
                    } else {
                        size_t crow = (size_t)gm + (size_t)(((unsigned)gm >> 11) + 1) * Ss;
                        if (gn < 4096) {
                            p1[crow * Dd + (gn - 2048)] = f2bf(v);       // kcat bf16
                            ntstore(&f0[crow * Dd + (gn - 2048)], v);    // cache_k f32
                        } else {
                            f1[crow * Dd + (gn - 4096)] = v;             // cache_v f32 (read by vup)
                        }
                    }
                } else if constexpr (MODE == MS) {
                    p0[(size_t)bz * Ss * Tcat + (size_t)gm * Tcat + gn] = f2bf(v);
                } else { // MPV
                    ntstore(&f0[(size_t)bz * Ss * Dd + (size_t)gm * Dd + gn],
                            rintf(v * 1e4f) * 1e-4f); // out: final -> stream
                }
            }
        }
    }
}

// ---------- softmax ----------
__global__ __launch_bounds__(256) void k_softmax(u16* __restrict__ SP) {
    const size_t row = blockIdx.x;
    u16* p = SP + row * Tcat;
    const int tid = threadIdx.x;
    const int lane = tid & 63;
    const int wv = tid >> 6;
    const float RS = 0.022097086912079608f; // 1/sqrt(2048)

    ushort4 raw[4];
    const ushort4* src = (const ushort4*)(p + tid * 16);
#pragma unroll
    for (int i = 0; i < 4; ++i) raw[i] = src[i];

    float v[16];
#pragma unroll
    for (int i = 0; i < 4; ++i) {
        v[i * 4 + 0] = bf2f(raw[i].x) * RS;
        v[i * 4 + 1] = bf2f(raw[i].y) * RS;
        v[i * 4 + 2] = bf2f(raw[i].z) * RS;
        v[i * 4 + 3] = bf2f(raw[i].w) * RS;
    }
    float mx = v[0];
#pragma unroll
    for (int i = 1; i < 16; ++i) mx = fmaxf(mx, v[i]);
#pragma unroll
    for (int s = 32; s; s >>= 1) mx = fmaxf(mx, __shfl_xor(mx, s));
    __shared__ float redm[4];
    if (lane == 0) redm[wv] = mx;
    __syncthreads();
    mx = fmaxf(fmaxf(redm[0], redm[1]), fmaxf(redm[2], redm[3]));

    float sum = 0.f;
#pragma unroll
    for (int i = 0; i < 16; ++i) {
        v[i] = __expf(v[i] - mx);
        sum += v[i];
    }
#pragma unroll
    for (int s = 32; s; s >>= 1) sum += __shfl_xor(sum, s);
    __shared__ float reds[4];
    if (lane == 0) reds[wv] = sum;
    __syncthreads();
    sum = reds[0] + reds[1] + reds[2] + reds[3];
    float inv = 1.0f / sum;

    ushort4* dst = (ushort4*)(p + tid * 16);
#pragma unroll
    for (int i = 0; i < 4; ++i) {
        ushort4 o;
        o.x = f2bf(v[i * 4 + 0] * inv);
        o.y = f2bf(v[i * 4 + 1] * inv);
        o.z = f2bf(v[i * 4 + 2] * inv);
        o.w = f2bf(v[i * 4 + 3] * inv);
        dst[i] = o;
    }
}

// ---------- launch ----------
extern "C" void kernel_launch(void* const* d_in, const int* in_sizes, int n_in,
                              void* d_out, int out_size, void* d_ws, size_t ws_size,
                              hipStream_t stream) {
    const float* x      = (const float*)d_in[0];
    const float* past_k = (const float*)d_in[1];
    const float* past_v = (const float*)d_in[2];
    const float* Wq     = (const float*)d_in[3];
    const float* Wk     = (const float*)d_in[4];
    const float* Wv     = (const float*)d_in[5];

    float* out     = (float*)d_out;
    float* cache_k = out + (size_t)Bb * Ss * Dd;
    float* cache_v = cache_k + (size_t)Bb * Tcat * Dd;

    u16* x_bf    = (u16*)d_ws;
    u16* wqkv_bf = x_bf + (size_t)Bb * Ss * Dd;
    u16* q_bf    = wqkv_bf + (size_t)3 * Dd * Dd;
    u16* kcat    = q_bf + (size_t)Bb * Ss * Dd;
    u16* vt      = kcat + (size_t)Bb * Tcat * Dd;
    u16* sp      = vt + (size_t)Bb * Dd * Tcat;

    // fused bf16 conversions (x + Wq/Wk/Wv in one dispatch)
    k_conv<<<16384 + 3 * 4096, 256, 0, stream>>>(x, Wq, Wk, Wv, x_bf, wqkv_bf);

    // fused QKV projection: M=8192, N=6144, K=2048 — 256^2 tile
    gemm8<MQKV><<<dim3(24, 32, 1), 512, 0, stream>>>(x_bf, wqkv_bf, Dd, 0, 0, 6, 16,
                                                     q_bf, kcat, cache_k, cache_v);

    // fused post-QKV streaming: pastK + pastV + newV transpose in one dispatch
    k_past<<<49152, 256, 0, stream>>>(past_k, past_v, cache_k, cache_v, kcat, vt);

    // scores: per b: M=2048, N=4096, K=2048 -> sp
    gemm8<MS><<<dim3(16, 8, Bb), 512, 0, stream>>>(q_bf, kcat, Dd,
                                                   (size_t)Ss * Dd, (size_t)Tcat * Dd, 8, 8,
                                                   sp, nullptr, nullptr, nullptr);
    // softmax rows
    k_softmax<<<Bb * Ss, 256, 0, stream>>>(sp);

    // PV: per b: M=2048, N=2048, K=4096 -> out (rounded)
    gemm8<MPV><<<dim3(8, 8, Bb), 512, 0, stream>>>(sp, vt, Tcat,
                                                   (size_t)Ss * Tcat, (size_t)Dd * Tcat, 8, 4,
                                                   nullptr, nullptr, out, nullptr);
}